// Round 2
// baseline (2527.212 us; speedup 1.0000x reference)
//
#include <hip/hip_runtime.h>

// NLIF fused step: I_tot = g@(w*nt[:,None]) + g_fast@W_fast + I_ext@W_in + I_tonic
// then elementwise neuron update -> 6 stacked outputs (readout, v, g, g_fast, s, theta_s).
// B=4096 (M), N=2048 (cols), K_total = 3*2048 = 6144.
//
// ROUND 1 CHANGE: fp64 accumulation + fp64 spike decision.
// Rationale: v_next straddles theta_s=1.0 densely; fp32 summation-order drift
// (~5e-5) flips ~50 spike flags vs the high-precision reference -> absmax ~2.
// fp64 makes v_next near-exact so spike decisions match the reference.

#define Bdim 4096
#define Ndim 2048
#define BM 128
#define BN 128
#define BK 32
#define LDA 132   // BM + 4 pad: 16B-aligned rows, conflict-free frag reads
#define LDB 132   // BN + 4 pad

__global__ __launch_bounds__(256, 2)
void nlif_kernel(const float* __restrict__ I_ext,
                 const float* __restrict__ v,
                 const float* __restrict__ g,
                 const float* __restrict__ g_fast,
                 const float* __restrict__ s,
                 const float* __restrict__ theta_s,
                 const float* __restrict__ w,
                 const float* __restrict__ W_fast,
                 const float* __restrict__ W_in,
                 const float* __restrict__ I_tonic,
                 const float* __restrict__ O,
                 const float* __restrict__ nt,
                 float* __restrict__ out)
{
    __shared__ float As[BK][LDA];   // transposed: As[k][row]
    __shared__ float Bs[BK][LDB];   // Bs[k][col]

    const int t  = threadIdx.x;
    const int tx = t & 15;          // column fragment
    const int ty = t >> 4;          // row fragment
    const int rowBase = blockIdx.y * BM;
    const int colBase = blockIdx.x * BN;

    const float* aSrc[3] = {g, g_fast, I_ext};
    const float* bSrc[3] = {w, W_fast, W_in};

    double acc[8][8];
    #pragma unroll
    for (int i = 0; i < 8; ++i)
        #pragma unroll
        for (int j = 0; j < 8; ++j)
            acc[i][j] = 0.0;

    float4 aReg[4], bReg[4];

    auto loadTile = [&](int tile) {
        const int sel = tile >> 6;            // 64 k-tiles per source
        const int kl  = (tile & 63) << 5;
        const float* __restrict__ A  = aSrc[sel];
        const float* __restrict__ Bp = bSrc[sel];
        #pragma unroll
        for (int i = 0; i < 4; ++i) {         // A: 128 rows x 32 cols
            int idx = t + 256 * i;
            int r   = idx >> 3;
            int c4  = idx & 7;
            aReg[i] = *(const float4*)(A + (size_t)(rowBase + r) * Ndim + kl + c4 * 4);
        }
        #pragma unroll
        for (int i = 0; i < 4; ++i) {         // B: 32 rows x 128 cols
            int idx = t + 256 * i;
            int r   = idx >> 5;
            int c4  = idx & 31;
            float4 bv = *(const float4*)(Bp + (size_t)(kl + r) * Ndim + colBase + c4 * 4);
            if (sel == 0) {                   // fold presynaptic sign into w rows
                float sc = nt[kl + r];
                bv.x *= sc; bv.y *= sc; bv.z *= sc; bv.w *= sc;
            }
            bReg[i] = bv;
        }
    };

    auto storeTile = [&]() {
        #pragma unroll
        for (int i = 0; i < 4; ++i) {         // A transposed into LDS
            int idx = t + 256 * i;
            int r   = idx >> 3;
            int c   = (idx & 7) * 4;
            As[c + 0][r] = aReg[i].x;
            As[c + 1][r] = aReg[i].y;
            As[c + 2][r] = aReg[i].z;
            As[c + 3][r] = aReg[i].w;
        }
        #pragma unroll
        for (int i = 0; i < 4; ++i) {         // B straight
            int idx = t + 256 * i;
            int r   = idx >> 5;
            int c   = (idx & 31) * 4;
            *(float4*)&Bs[r][c] = bReg[i];
        }
    };

    loadTile(0);
    storeTile();
    __syncthreads();

    const int NT = (3 * Ndim) / BK;           // 192 k-tiles
    for (int tile = 0; tile < NT; ++tile) {
        if (tile + 1 < NT) loadTile(tile + 1);   // reg prefetch overlaps compute

        #pragma unroll 8
        for (int k = 0; k < BK; ++k) {
            float4 a0 = *(const float4*)&As[k][ty * 4];
            float4 a1 = *(const float4*)&As[k][ty * 4 + 64];
            float4 b0 = *(const float4*)&Bs[k][tx * 4];
            float4 b1 = *(const float4*)&Bs[k][tx * 4 + 64];
            double ad[8] = {(double)a0.x, (double)a0.y, (double)a0.z, (double)a0.w,
                            (double)a1.x, (double)a1.y, (double)a1.z, (double)a1.w};
            double bd[8] = {(double)b0.x, (double)b0.y, (double)b0.z, (double)b0.w,
                            (double)b1.x, (double)b1.y, (double)b1.z, (double)b1.w};
            #pragma unroll
            for (int ri = 0; ri < 8; ++ri)
                #pragma unroll
                for (int cj = 0; cj < 8; ++cj)
                    acc[ri][cj] = fma(ad[ri], bd[cj], acc[ri][cj]);
        }

        if (tile + 1 < NT) {
            __syncthreads();
            storeTile();
            __syncthreads();
        }
    }

    // ---- fused elementwise epilogue (fp64 decisions) -> 6 output slabs ----
    const size_t SLAB = (size_t)Bdim * Ndim;
    float* out_ro = out;
    float* out_v  = out + SLAB;
    float* out_g  = out + 2 * SLAB;
    float* out_gf = out + 3 * SLAB;
    float* out_s  = out + 4 * SLAB;
    float* out_th = out + 5 * SLAB;

    #pragma unroll
    for (int ri = 0; ri < 8; ++ri) {
        int row = rowBase + ty * 4 + (ri & 3) + ((ri >> 2) << 6);
        #pragma unroll
        for (int cg = 0; cg < 2; ++cg) {
            int col = colBase + tx * 4 + cg * 64;
            size_t off = (size_t)row * Ndim + col;

            float4 ton = *(const float4*)(I_tonic + col);
            float4 o4  = *(const float4*)(O + col);
            float4 v4  = *(const float4*)(v + off);
            float4 s4  = *(const float4*)(s + off);
            float4 g4  = *(const float4*)(g + off);
            float4 gf4 = *(const float4*)(g_fast + off);
            float4 th4 = *(const float4*)(theta_s + off);

            float4 ro, vn, gn, gfn, sn, thn;

#define NLIF_COMP(X, J)                                                       \
            {                                                                 \
                double Itot   = acc[ri][cg * 4 + J] + (double)ton.X;          \
                double dvv    = (0.0 - (double)v4.X + Itot) / 10.0;           \
                double v_next = (double)v4.X + dvv;                           \
                double gating = fmin(fmax(v_next, 0.0), 1.0);                 \
                double dvc    = fmin(fmax(dvv, 0.0), 1.0);                    \
                double s_new  = (double)s4.X + (-(double)s4.X + gating * dvc) / 10.0; \
                bool   sp     = (v_next >= (double)th4.X);                    \
                ro.X  = (float)((double)o4.X * s_new);                        \
                vn.X  = (float)(sp ? (0.14 * (double)v4.X - 0.12) : v_next);  \
                gn.X  = (float)(sp ? 1.0 : (-(double)g4.X / 10.0));           \
                gfn.X = (float)(sp ? 1.0 : -(double)gf4.X);                   \
                sn.X  = (float)s_new;                                         \
                thn.X = (float)(0.7 * (double)th4.X + (sp ? 0.1 : 0.0));      \
            }
            NLIF_COMP(x, 0) NLIF_COMP(y, 1) NLIF_COMP(z, 2) NLIF_COMP(w, 3)
#undef NLIF_COMP

            *(float4*)(out_ro + off) = ro;
            *(float4*)(out_v  + off) = vn;
            *(float4*)(out_g  + off) = gn;
            *(float4*)(out_gf + off) = gfn;
            *(float4*)(out_s  + off) = sn;
            *(float4*)(out_th + off) = thn;
        }
    }
}

extern "C" void kernel_launch(void* const* d_in, const int* in_sizes, int n_in,
                              void* d_out, int out_size, void* d_ws, size_t ws_size,
                              hipStream_t stream) {
    const float* I_ext   = (const float*)d_in[0];
    const float* v       = (const float*)d_in[1];
    const float* g       = (const float*)d_in[2];
    const float* g_fast  = (const float*)d_in[3];
    const float* s       = (const float*)d_in[4];
    const float* theta_s = (const float*)d_in[5];
    const float* w       = (const float*)d_in[6];
    const float* W_fast  = (const float*)d_in[7];
    const float* W_in    = (const float*)d_in[8];
    const float* I_tonic = (const float*)d_in[9];
    const float* O       = (const float*)d_in[10];
    const float* nt      = (const float*)d_in[11];
    float* out           = (float*)d_out;

    dim3 grid(Ndim / BN, Bdim / BM);   // (16, 32) = 512 blocks
    dim3 block(256);
    nlif_kernel<<<grid, block, 0, stream>>>(I_ext, v, g, g_fast, s, theta_s,
                                            w, W_fast, W_in, I_tonic, O, nt, out);
}

// Round 5
// 1097.153 us; speedup vs baseline: 2.3034x; 2.3034x over previous
//
#include <hip/hip_runtime.h>

// NLIF fused step, two-pass mixed precision:
//   pass1: bf16 hi/lo-split MFMA GEMM (3 products: hh+hl+lh) + fused fp32 epilogue,
//          flags |v_next - theta_s| < DELTA into a worklist (expected ~1e4 of 8.4M).
//   pass2: fp64 recompute of flagged elements (exact spike decisions vs fp64 reference).
// Fallback: round-2 fp64 vector kernel if ws_size is too small for the worklist.
// (Resubmission: rounds 3 and 4 both failed on GPU acquisition, not on the kernel.)

#define Mdim 4096
#define Ndim 2048
#define Kdim 2048          // per source; 3 sources
#define BM 128
#define BN 128
#define BK 32
#define LDT 40             // LDS row stride in bf16 elems (80B rows: 5 granules, coprime to 8 -> conflict-free b128 reads)
#define DELTA 1.5e-3f

typedef __attribute__((ext_vector_type(8))) short bf16x8;
typedef __attribute__((ext_vector_type(4))) float f32x4;

__device__ __forceinline__ ushort f2bf_rne(float f) {
    uint u = __float_as_uint(f);
    uint r = u + 0x7FFFu + ((u >> 16) & 1u);
    return (ushort)(r >> 16);
}
__device__ __forceinline__ float bf2f(ushort h) {
    return __uint_as_float(((uint)h) << 16);
}

// ---------------- pass 1: MFMA GEMM + epilogue + flagging ----------------
__global__ __launch_bounds__(256, 2)
void nlif_pass1(const float* __restrict__ I_ext,
                const float* __restrict__ v,
                const float* __restrict__ g,
                const float* __restrict__ g_fast,
                const float* __restrict__ s,
                const float* __restrict__ theta_s,
                const float* __restrict__ w,
                const float* __restrict__ W_fast,
                const float* __restrict__ W_in,
                const float* __restrict__ I_tonic,
                const float* __restrict__ O,
                const float* __restrict__ nt,
                uint* __restrict__ counter,
                uint* __restrict__ wl, int cap,
                float* __restrict__ out)
{
    __shared__ ushort Ah[BM][LDT];   // A hi, row-major in k
    __shared__ ushort Al[BM][LDT];   // A lo
    __shared__ ushort Bh[BN][LDT];   // B hi, TRANSPOSED tile: [col][k]
    __shared__ ushort Bl[BN][LDT];   // B lo

    const int t    = threadIdx.x;
    const int lane = t & 63;
    const int wid  = t >> 6;
    const int wr   = wid >> 1;          // wave row 0..1
    const int wc   = wid & 1;           // wave col 0..1

    // XCD-aware swizzle (512 blocks = 8 XCDs x 64, bijective)
    int lin = blockIdx.y * 16 + blockIdx.x;
    int swz = (lin & 7) * 64 + (lin >> 3);
    const int rowBase = (swz >> 4) * BM;
    const int colBase = (swz & 15) * BN;

    const float* aSrc[3] = {g, g_fast, I_ext};
    const float* bSrc[3] = {w, W_fast, W_in};

    f32x4 acc[4][4];
    #pragma unroll
    for (int i = 0; i < 4; ++i)
        #pragma unroll
        for (int j = 0; j < 4; ++j)
            acc[i][j] = (f32x4){0.f, 0.f, 0.f, 0.f};

    // staging registers
    float4 fA[4];
    float  fB[16];

    const int rA = t >> 1;              // A row 0..127
    const int hA = (t & 1) << 4;        // k half offset 0/16
    const int cB = t & 127;             // B col 0..127
    const int kgB = (t >> 7) << 4;      // k group offset 0/16

    auto load_regs = [&](int tile) {
        const int sel = tile >> 6;
        const int kl  = (tile & 63) << 5;
        const float* Ap = aSrc[sel] + (size_t)(rowBase + rA) * Ndim + kl + hA;
        #pragma unroll
        for (int i = 0; i < 4; ++i) fA[i] = *(const float4*)(Ap + 4 * i);
        const float* Bp = bSrc[sel];
        if (sel == 0) {
            #pragma unroll
            for (int kk = 0; kk < 16; ++kk) {
                int k = kl + kgB + kk;
                fB[kk] = Bp[(size_t)k * Ndim + colBase + cB] * nt[k];
            }
        } else {
            #pragma unroll
            for (int kk = 0; kk < 16; ++kk) {
                int k = kl + kgB + kk;
                fB[kk] = Bp[(size_t)k * Ndim + colBase + cB];
            }
        }
    };

    auto write_lds = [&]() {
        #pragma unroll
        for (int i = 0; i < 4; ++i) {
            float e[4] = {fA[i].x, fA[i].y, fA[i].z, fA[i].w};
            ushort4 hi, lo;
            ushort h0 = f2bf_rne(e[0]), h1 = f2bf_rne(e[1]),
                   h2 = f2bf_rne(e[2]), h3 = f2bf_rne(e[3]);
            hi.x = h0; hi.y = h1; hi.z = h2; hi.w = h3;
            lo.x = f2bf_rne(e[0] - bf2f(h0));
            lo.y = f2bf_rne(e[1] - bf2f(h1));
            lo.z = f2bf_rne(e[2] - bf2f(h2));
            lo.w = f2bf_rne(e[3] - bf2f(h3));
            *(ushort4*)&Ah[rA][hA + 4 * i] = hi;
            *(ushort4*)&Al[rA][hA + 4 * i] = lo;
        }
        #pragma unroll
        for (int q = 0; q < 4; ++q) {
            ushort4 hi, lo;
            ushort h0 = f2bf_rne(fB[4*q+0]), h1 = f2bf_rne(fB[4*q+1]),
                   h2 = f2bf_rne(fB[4*q+2]), h3 = f2bf_rne(fB[4*q+3]);
            hi.x = h0; hi.y = h1; hi.z = h2; hi.w = h3;
            lo.x = f2bf_rne(fB[4*q+0] - bf2f(h0));
            lo.y = f2bf_rne(fB[4*q+1] - bf2f(h1));
            lo.z = f2bf_rne(fB[4*q+2] - bf2f(h2));
            lo.w = f2bf_rne(fB[4*q+3] - bf2f(h3));
            *(ushort4*)&Bh[cB][kgB + 4 * q] = hi;
            *(ushort4*)&Bl[cB][kgB + 4 * q] = lo;
        }
    };

    load_regs(0);
    write_lds();
    __syncthreads();

    const int NT = 3 * Kdim / BK;       // 192
    const int l15  = lane & 15;
    const int koff = (lane >> 4) << 3;  // 0/8/16/24

    for (int tile = 0; tile < NT; ++tile) {
        if (tile + 1 < NT) load_regs(tile + 1);

        bf16x8 ah[4], al[4], bh[4], bl[4];
        #pragma unroll
        for (int f = 0; f < 4; ++f) {
            int ar = wr * 64 + f * 16 + l15;
            ah[f] = *(const bf16x8*)&Ah[ar][koff];
            al[f] = *(const bf16x8*)&Al[ar][koff];
            int bc = wc * 64 + f * 16 + l15;
            bh[f] = *(const bf16x8*)&Bh[bc][koff];
            bl[f] = *(const bf16x8*)&Bl[bc][koff];
        }
        #pragma unroll
        for (int i = 0; i < 4; ++i)
            #pragma unroll
            for (int j = 0; j < 4; ++j) {
                acc[i][j] = __builtin_amdgcn_mfma_f32_16x16x32_bf16(ah[i], bh[j], acc[i][j], 0, 0, 0);
                acc[i][j] = __builtin_amdgcn_mfma_f32_16x16x32_bf16(ah[i], bl[j], acc[i][j], 0, 0, 0);
                acc[i][j] = __builtin_amdgcn_mfma_f32_16x16x32_bf16(al[i], bh[j], acc[i][j], 0, 0, 0);
            }

        if (tile + 1 < NT) {
            __syncthreads();
            write_lds();
            __syncthreads();
        }
    }

    // ---- fused fp32 epilogue; C/D layout: col=lane&15, row=(lane>>4)*4+p ----
    const size_t SLAB = (size_t)Mdim * Ndim;
    float* out_ro = out;
    float* out_v  = out + SLAB;
    float* out_g  = out + 2 * SLAB;
    float* out_gf = out + 3 * SLAB;
    float* out_s  = out + 4 * SLAB;
    float* out_th = out + 5 * SLAB;

    const int rowF = ((lane >> 4) << 2);
    #pragma unroll
    for (int i = 0; i < 4; ++i) {
        #pragma unroll
        for (int j = 0; j < 4; ++j) {
            int col = colBase + wc * 64 + j * 16 + l15;
            float ton = I_tonic[col];
            float ov  = O[col];
            #pragma unroll
            for (int p = 0; p < 4; ++p) {
                int row = rowBase + wr * 64 + i * 16 + rowF + p;
                size_t off = (size_t)row * Ndim + col;
                float Itot   = acc[i][j][p] + ton;
                float vv     = v[off];
                float dv     = (Itot - vv) * 0.1f;
                float v_next = vv + dv;
                float gating = fminf(fmaxf(v_next, 0.f), 1.f);
                float dvc    = fminf(fmaxf(dv, 0.f), 1.f);
                float sv     = s[off];
                float s_new  = sv + (gating * dvc - sv) * 0.1f;
                float th     = theta_s[off];
                bool  sp     = (v_next >= th);
                out_ro[off] = ov * s_new;
                out_v [off] = sp ? fmaf(0.14f, vv, -0.12f) : v_next;
                out_g [off] = sp ? 1.f : (-g[off] * 0.1f);
                out_gf[off] = sp ? 1.f : (-g_fast[off]);
                out_s [off] = s_new;
                out_th[off] = 0.7f * th + (sp ? 0.1f : 0.f);
                if (fabsf(v_next - th) < DELTA) {
                    uint idx = atomicAdd(counter, 1u);
                    if (idx < (uint)cap) wl[idx] = ((uint)row << 11) | (uint)col;
                }
            }
        }
    }
}

// ---------------- pass 2: fp64 fixup of flagged elements ----------------
__device__ __forceinline__ float ldw(const float* p, int c, int k, int tmode) {
    return tmode ? p[(size_t)c * Kdim + k] : p[(size_t)k * Ndim + c];
}

__global__ __launch_bounds__(256)
void nlif_fixup(const float* __restrict__ I_ext,
                const float* __restrict__ v,
                const float* __restrict__ g,
                const float* __restrict__ g_fast,
                const float* __restrict__ s,
                const float* __restrict__ theta_s,
                const float* __restrict__ w0,   // w  (or wT)
                const float* __restrict__ w1,   // W_fast (or T)
                const float* __restrict__ w2,   // W_in (or T)
                int tmode,
                const float* __restrict__ I_tonic,
                const float* __restrict__ O,
                const float* __restrict__ nt,
                const uint* __restrict__ counter,
                const uint* __restrict__ wl, int cap,
                float* __restrict__ out)
{
    uint cnt = *counter;
    int n = (int)(cnt < (uint)cap ? cnt : (uint)cap);
    int wgid = (int)((blockIdx.x * blockDim.x + threadIdx.x) >> 6);
    int lane = threadIdx.x & 63;
    int nw   = (int)((gridDim.x * blockDim.x) >> 6);
    const size_t SLAB = (size_t)Mdim * Ndim;

    for (int e = wgid; e < n; e += nw) {
        uint u = wl[e];
        int r = (int)(u >> 11), c = (int)(u & 2047);
        double acc = 0.0;
        for (int k = lane; k < Kdim; k += 64) {
            size_t ro = (size_t)r * Ndim + k;
            double wsyn = (double)ldw(w0, c, k, tmode) * (double)nt[k];   // exact in fp64
            acc += (double)g[ro] * wsyn;
            acc += (double)g_fast[ro] * (double)ldw(w1, c, k, tmode);
            acc += (double)I_ext[ro] * (double)ldw(w2, c, k, tmode);
        }
        #pragma unroll
        for (int m = 32; m; m >>= 1) acc += __shfl_xor(acc, m);

        if (lane == 0) {
            size_t off = (size_t)r * Ndim + c;
            double vv = (double)v[off], sv = (double)s[off], tv = (double)theta_s[off];
            double Itot   = acc + (double)I_tonic[c];
            double dvv    = (0.0 - vv + Itot) / 10.0;
            double v_next = vv + dvv;
            double gating = fmin(fmax(v_next, 0.0), 1.0);
            double dvc    = fmin(fmax(dvv, 0.0), 1.0);
            double s_new  = sv + (-sv + gating * dvc) / 10.0;
            bool   sp     = (v_next >= tv);
            out[off]            = (float)((double)O[c] * s_new);
            out[off + SLAB]     = (float)(sp ? (0.14 * vv - 0.12) : v_next);
            out[off + 2 * SLAB] = (float)(sp ? 1.0 : (-(double)g[off] / 10.0));
            out[off + 3 * SLAB] = (float)(sp ? 1.0 : -(double)g_fast[off]);
            out[off + 4 * SLAB] = (float)s_new;
            out[off + 5 * SLAB] = (float)(0.7 * tv + (sp ? 0.1 : 0.0));
        }
    }
}

// ---------------- helpers ----------------
__global__ void zero_cnt(uint* c) { *c = 0u; }

__global__ __launch_bounds__(256)
void transpose_k(const float* __restrict__ in, float* __restrict__ out) {
    __shared__ float tile[32][33];
    int bx = blockIdx.x * 32, by = blockIdx.y * 32;
    int tx = threadIdx.x & 31, ty = threadIdx.x >> 5;   // 32x8
    #pragma unroll
    for (int i = 0; i < 4; ++i)
        tile[ty + 8 * i][tx] = in[(size_t)(by + ty + 8 * i) * Ndim + bx + tx];
    __syncthreads();
    #pragma unroll
    for (int i = 0; i < 4; ++i)
        out[(size_t)(bx + ty + 8 * i) * Ndim + by + tx] = tile[tx][ty + 8 * i];
}

// ---------------- fallback: round-2 fp64 vector kernel (known-passing) ----------------
#define LDAF 132
#define LDBF 132
__global__ __launch_bounds__(256, 2)
void nlif_fp64(const float* __restrict__ I_ext, const float* __restrict__ v,
               const float* __restrict__ g, const float* __restrict__ g_fast,
               const float* __restrict__ s, const float* __restrict__ theta_s,
               const float* __restrict__ w, const float* __restrict__ W_fast,
               const float* __restrict__ W_in, const float* __restrict__ I_tonic,
               const float* __restrict__ O, const float* __restrict__ nt,
               float* __restrict__ out)
{
    __shared__ float As[BK][LDAF];
    __shared__ float Bs[BK][LDBF];
    const int t = threadIdx.x, tx = t & 15, ty = t >> 4;
    const int rowBase = blockIdx.y * BM, colBase = blockIdx.x * BN;
    const float* aSrc[3] = {g, g_fast, I_ext};
    const float* bSrc[3] = {w, W_fast, W_in};
    double acc[8][8];
    #pragma unroll
    for (int i = 0; i < 8; ++i)
        #pragma unroll
        for (int j = 0; j < 8; ++j) acc[i][j] = 0.0;
    float4 aReg[4], bReg[4];
    auto loadTile = [&](int tile) {
        const int sel = tile >> 6, kl = (tile & 63) << 5;
        const float* A = aSrc[sel]; const float* Bp = bSrc[sel];
        #pragma unroll
        for (int i = 0; i < 4; ++i) {
            int idx = t + 256 * i, r = idx >> 3, c4 = idx & 7;
            aReg[i] = *(const float4*)(A + (size_t)(rowBase + r) * Ndim + kl + c4 * 4);
        }
        #pragma unroll
        for (int i = 0; i < 4; ++i) {
            int idx = t + 256 * i, r = idx >> 5, c4 = idx & 31;
            float4 bv = *(const float4*)(Bp + (size_t)(kl + r) * Ndim + colBase + c4 * 4);
            if (sel == 0) { float sc = nt[kl + r]; bv.x *= sc; bv.y *= sc; bv.z *= sc; bv.w *= sc; }
            bReg[i] = bv;
        }
    };
    auto storeTile = [&]() {
        #pragma unroll
        for (int i = 0; i < 4; ++i) {
            int idx = t + 256 * i, r = idx >> 3, c = (idx & 7) * 4;
            As[c][r] = aReg[i].x; As[c + 1][r] = aReg[i].y;
            As[c + 2][r] = aReg[i].z; As[c + 3][r] = aReg[i].w;
        }
        #pragma unroll
        for (int i = 0; i < 4; ++i) {
            int idx = t + 256 * i, r = idx >> 5, c = (idx & 31) * 4;
            *(float4*)&Bs[r][c] = bReg[i];
        }
    };
    loadTile(0); storeTile(); __syncthreads();
    const int NT = 3 * Kdim / BK;
    for (int tile = 0; tile < NT; ++tile) {
        if (tile + 1 < NT) loadTile(tile + 1);
        #pragma unroll 8
        for (int k = 0; k < BK; ++k) {
            float4 a0 = *(const float4*)&As[k][ty * 4];
            float4 a1 = *(const float4*)&As[k][ty * 4 + 64];
            float4 b0 = *(const float4*)&Bs[k][tx * 4];
            float4 b1 = *(const float4*)&Bs[k][tx * 4 + 64];
            double ad[8] = {a0.x, a0.y, a0.z, a0.w, a1.x, a1.y, a1.z, a1.w};
            double bd[8] = {b0.x, b0.y, b0.z, b0.w, b1.x, b1.y, b1.z, b1.w};
            #pragma unroll
            for (int ri = 0; ri < 8; ++ri)
                #pragma unroll
                for (int cj = 0; cj < 8; ++cj)
                    acc[ri][cj] = fma(ad[ri], bd[cj], acc[ri][cj]);
        }
        if (tile + 1 < NT) { __syncthreads(); storeTile(); __syncthreads(); }
    }
    const size_t SLAB = (size_t)Mdim * Ndim;
    #pragma unroll
    for (int ri = 0; ri < 8; ++ri) {
        int row = rowBase + ty * 4 + (ri & 3) + ((ri >> 2) << 6);
        #pragma unroll
        for (int cg = 0; cg < 2; ++cg) {
            int col = colBase + tx * 4 + cg * 64;
            size_t off = (size_t)row * Ndim + col;
            #pragma unroll
            for (int e = 0; e < 4; ++e) {
                size_t o = off + e;
                double Itot   = acc[ri][cg * 4 + e] + (double)I_tonic[col + e];
                double vv = v[o], sv = s[o], tv = theta_s[o];
                double dvv    = (0.0 - vv + Itot) / 10.0;
                double v_next = vv + dvv;
                double gating = fmin(fmax(v_next, 0.0), 1.0);
                double dvc    = fmin(fmax(dvv, 0.0), 1.0);
                double s_new  = sv + (-sv + gating * dvc) / 10.0;
                bool   sp     = (v_next >= tv);
                out[o]            = (float)((double)O[col + e] * s_new);
                out[o + SLAB]     = (float)(sp ? (0.14 * vv - 0.12) : v_next);
                out[o + 2 * SLAB] = (float)(sp ? 1.0 : (-(double)g[o] / 10.0));
                out[o + 3 * SLAB] = (float)(sp ? 1.0 : -(double)g_fast[o]);
                out[o + 4 * SLAB] = (float)s_new;
                out[o + 5 * SLAB] = (float)(0.7 * tv + (sp ? 0.1 : 0.0));
            }
        }
    }
}

extern "C" void kernel_launch(void* const* d_in, const int* in_sizes, int n_in,
                              void* d_out, int out_size, void* d_ws, size_t ws_size,
                              hipStream_t stream) {
    const float* I_ext   = (const float*)d_in[0];
    const float* v       = (const float*)d_in[1];
    const float* g       = (const float*)d_in[2];
    const float* g_fast  = (const float*)d_in[3];
    const float* s       = (const float*)d_in[4];
    const float* theta_s = (const float*)d_in[5];
    const float* w       = (const float*)d_in[6];
    const float* W_fast  = (const float*)d_in[7];
    const float* W_in    = (const float*)d_in[8];
    const float* I_tonic = (const float*)d_in[9];
    const float* O       = (const float*)d_in[10];
    const float* nt      = (const float*)d_in[11];
    float* out           = (float*)d_out;

    if (ws_size < (1u << 20)) {   // no room for worklist -> known-good fp64 path
        dim3 grid(Ndim / BN, Mdim / BM);
        nlif_fp64<<<grid, 256, 0, stream>>>(I_ext, v, g, g_fast, s, theta_s,
                                            w, W_fast, W_in, I_tonic, O, nt, out);
        return;
    }

    uint8_t* ws = (uint8_t*)d_ws;
    const size_t TSZ = (size_t)Kdim * Ndim * sizeof(float);   // 16.78 MB
    uint* counter = (uint*)ws;
    int tmode = (ws_size >= 256 + 3 * TSZ + (1u << 20)) ? 1 : 0;

    float *w0, *w1, *w2; uint* wl; size_t cap;
    if (tmode) {
        w0 = (float*)(ws + 256);
        w1 = w0 + (size_t)Kdim * Ndim;
        w2 = w1 + (size_t)Kdim * Ndim;
        wl = (uint*)(ws + 256 + 3 * TSZ);
        cap = (ws_size - 256 - 3 * TSZ) / 4;
    } else {
        w0 = (float*)w; w1 = (float*)W_fast; w2 = (float*)W_in;
        wl = (uint*)(ws + 256);
        cap = (ws_size - 256) / 4;
    }
    if (cap > (1u << 20)) cap = (1u << 20);

    zero_cnt<<<1, 1, 0, stream>>>(counter);
    if (tmode) {
        dim3 tg(Ndim / 32, Kdim / 32);
        transpose_k<<<tg, 256, 0, stream>>>(w, w0);
        transpose_k<<<tg, 256, 0, stream>>>(W_fast, w1);
        transpose_k<<<tg, 256, 0, stream>>>(W_in, w2);
    }
    dim3 grid(Ndim / BN, Mdim / BM);   // (16, 32) = 512 blocks, exactly 2/CU
    nlif_pass1<<<grid, 256, 0, stream>>>(I_ext, v, g, g_fast, s, theta_s,
                                         w, W_fast, W_in, I_tonic, O, nt,
                                         counter, wl, (int)cap, out);
    nlif_fixup<<<256, 256, 0, stream>>>(I_ext, v, g, g_fast, s, theta_s,
                                        w0, w1, w2, tmode, I_tonic, O, nt,
                                        counter, wl, (int)cap, out);
}